// Round 2
// baseline (437.548 us; speedup 1.0000x reference)
//
#include <hip/hip_runtime.h>

#define NCOEF 66           // n = 70 - 3 - 1 usable coefficients

typedef float f32x4 __attribute__((ext_vector_type(4)));

// Uniform knots t[k] = k/69. De Boor (p=3) on uniform knots == uniform cubic
// B-spline. Per interval i (clamped to [3,65]) with s = 69*x - i:
//   a0 = (c0 + 4c1 + c2)/6,  a1 = (c2 - c0)/2,
//   a2 = (c0 - 2c1 + c2)/2,  a3 = (c3 - c0 + 3(c1 - c2))/6
//   f  = ((a3*s + a2)*s + a1)*s + a0     (3 fma Horner; exact for s<0 / s>1
//   so boundary clamping extrapolates identically to de Boor)

__global__ __launch_bounds__(256) void spline_kernel(
    const float* __restrict__ x, const float* __restrict__ coef,
    float* __restrict__ out, int n)
{
    __shared__ float  sc[NCOEF];
    __shared__ float4 tab[NCOEF];   // 16B-aligned -> one ds_read_b128 per elem

    const int t = threadIdx.x;
    if (t < NCOEF) sc[t] = coef[t];
    __syncthreads();
    if (t >= 3 && t < NCOEF) {
        float c0 = sc[t - 3], c1 = sc[t - 2], c2 = sc[t - 1], c3 = sc[t];
        const float k6 = 1.0f / 6.0f;
        float a0 = (c0 + 4.0f * c1 + c2) * k6;
        float a1 = (c2 - c0) * 0.5f;
        float a2 = (c0 - 2.0f * c1 + c2) * 0.5f;
        float a3 = (c3 - c0 + 3.0f * (c1 - c2)) * k6;
        tab[t] = make_float4(a0, a1, a2, a3);
    }
    __syncthreads();

    const int n4     = n >> 2;
    const int stride = gridDim.x * blockDim.x;
    const int gid    = blockIdx.x * blockDim.x + threadIdx.x;

    const long g = (long)gid, st = (long)stride;

    // Fast path: this thread's grid-stride chain is EXACTLY 8 float4s.
    // Load all 8 up front -> 8 outstanding VMEM ops per wave (8x MLP vs the
    // old 1-in-flight serial chain that capped us at ~1.2 TB/s).
    if (g + 7 * st < (long)n4 && g + 8 * st >= (long)n4) {
        const f32x4* __restrict__ xp = reinterpret_cast<const f32x4*>(x);
        f32x4*       __restrict__ op = reinterpret_cast<f32x4*>(out);

        f32x4 v[8];
        #pragma unroll
        for (int k = 0; k < 8; ++k)
            v[k] = __builtin_nontemporal_load(xp + gid + k * stride);

        #pragma unroll
        for (int k = 0; k < 8; ++k) {
            f32x4 ov;
            #pragma unroll
            for (int e = 0; e < 4; ++e) {
                float xs = v[k][e] * 69.0f;
                int   i  = (int)xs;                 // trunc; negatives clamp below
                i = i < 3 ? 3 : (i > 65 ? 65 : i);
                float s  = xs - (float)i;
                float4 a = tab[i];
                ov[e] = fmaf(fmaf(fmaf(a.w, s, a.z), s, a.y), s, a.x);
            }
            __builtin_nontemporal_store(ov, op + gid + k * stride);
        }
    } else {
        // generic grid-stride fallback (any n / grid shape)
        for (int idx = gid; idx < n4; idx += stride) {
            float4 xv = reinterpret_cast<const float4*>(x)[idx];
            float4 ov;
            #pragma unroll
            for (int e = 0; e < 4; ++e) {
                float xs = (&xv.x)[e] * 69.0f;
                int   i  = (int)xs;
                i = i < 3 ? 3 : (i > 65 ? 65 : i);
                float s  = xs - (float)i;
                float4 a = tab[i];
                (&ov.x)[e] = fmaf(fmaf(fmaf(a.w, s, a.z), s, a.y), s, a.x);
            }
            reinterpret_cast<float4*>(out)[idx] = ov;
        }
    }

    // generic scalar tail (n % 4 != 0) — no-op for this problem's n
    for (int k = (n4 << 2) + gid; k < n; k += stride) {
        float xs = x[k] * 69.0f;
        int   i  = (int)xs;
        i = i < 3 ? 3 : (i > 65 ? 65 : i);
        float s  = xs - (float)i;
        float4 a = tab[i];
        out[k] = fmaf(fmaf(fmaf(a.w, s, a.z), s, a.y), s, a.x);
    }
}

extern "C" void kernel_launch(void* const* d_in, const int* in_sizes, int n_in,
                              void* d_out, int out_size, void* d_ws, size_t ws_size,
                              hipStream_t stream) {
    const float* x    = (const float*)d_in[0];
    const float* coef = (const float*)d_in[1];
    float* out        = (float*)d_out;
    int n = in_sizes[0];

    // 8192 blocks x 256 thr = 2.097M threads; 16.77M float4 -> exactly 8
    // float4/thread, so every thread takes the 8-deep batched fast path.
    int threads = 256;
    int blocks  = 8192;
    int max_blocks = ((n >> 2) + threads - 1) / threads;
    if (max_blocks < 1) max_blocks = 1;
    if (blocks > max_blocks) blocks = max_blocks;

    spline_kernel<<<blocks, threads, 0, stream>>>(x, coef, out, n);
}

// Round 3
// 431.120 us; speedup vs baseline: 1.0149x; 1.0149x over previous
//
#include <hip/hip_runtime.h>

#define NCOEF 66           // n = 70 - 3 - 1 usable coefficients
#define TABB  (NCOEF + 2)  // second table copy at float4-index 68 ->
                           // dword offset 272 ≡ 16 (mod 32): +16-bank rotation

// Uniform knots t[k] = k/69. De Boor (p=3) on uniform knots == uniform cubic
// B-spline. Per interval i (clamped to [3,65]) with s = 69*x - i:
//   a0 = (c0 + 4c1 + c2)/6,  a1 = (c2 - c0)/2,
//   a2 = (c0 - 2c1 + c2)/2,  a3 = (c3 - c0 + 3(c1 - c2))/6
//   f  = ((a3*s + a2)*s + a1)*s + a0   (3-fma Horner; exact polynomial
//   identity, so boundary clamping extrapolates identically to de Boor)
//
// LDS layout: two copies of the 66-entry float4 table, copy B rotated by
// 16 banks. Even lanes gather from copy A, odd lanes from copy B -> the
// data-dependent bank-conflict set is halved per parity class, and the
// i=3 (52% of lanes) / i=65 (17%) broadcast crowds land in disjoint
// bank groups for even vs odd lanes.

__global__ __launch_bounds__(256) void spline_kernel(
    const float* __restrict__ x, const float* __restrict__ coef,
    float* __restrict__ out, int n)
{
    __shared__ float  sc[NCOEF];
    __shared__ float4 tab[TABB + NCOEF];

    const int t = threadIdx.x;
    if (t < NCOEF) sc[t] = coef[t];
    __syncthreads();
    if (t >= 3 && t < NCOEF) {
        float c0 = sc[t - 3], c1 = sc[t - 2], c2 = sc[t - 1], c3 = sc[t];
        const float k6 = 1.0f / 6.0f;
        float a0 = (c0 + 4.0f * c1 + c2) * k6;
        float a1 = (c2 - c0) * 0.5f;
        float a2 = (c0 - 2.0f * c1 + c2) * 0.5f;
        float a3 = (c3 - c0 + 3.0f * (c1 - c2)) * k6;
        float4 a = make_float4(a0, a1, a2, a3);
        tab[t]        = a;
        tab[TABB + t] = a;
    }
    __syncthreads();

    const int n4     = n >> 2;
    const int stride = gridDim.x * blockDim.x;
    const int gid    = blockIdx.x * blockDim.x + threadIdx.x;
    const int tb     = (t & 1) ? TABB : 0;   // per-lane table base (parity)

    const float4* __restrict__ xp = reinterpret_cast<const float4*>(x);
    float4*       __restrict__ op = reinterpret_cast<float4*>(out);

    int start = gid;

    // Fast path: this thread has (at least) 8 full float4s at grid stride.
    // With the launch config below every thread has EXACTLY 8.
    if (gid + 7 * stride < n4) {
        float4 v[8];
        #pragma unroll
        for (int k = 0; k < 8; ++k)
            v[k] = xp[gid + k * stride];

        #pragma unroll
        for (int k = 0; k < 8; ++k) {
            float4 ov;
            #pragma unroll
            for (int e = 0; e < 4; ++e) {
                float xs = (&v[k].x)[e] * 69.0f;
                float fi = floorf(xs);
                fi = fi < 3.0f ? 3.0f : (fi > 65.0f ? 65.0f : fi);  // v_med3
                float s  = xs - fi;                // exact for extrapolation
                float4 a = tab[tb + (int)fi];
                (&ov.x)[e] = fmaf(fmaf(fmaf(a.w, s, a.z), s, a.y), s, a.x);
            }
            op[gid + k * stride] = ov;
        }
        start = gid + 8 * stride;
    }

    // generic grid-stride remainder (no-op when grid exactly tiles n4)
    for (int idx = start; idx < n4; idx += stride) {
        float4 xv = xp[idx];
        float4 ov;
        #pragma unroll
        for (int e = 0; e < 4; ++e) {
            float xs = (&xv.x)[e] * 69.0f;
            float fi = floorf(xs);
            fi = fi < 3.0f ? 3.0f : (fi > 65.0f ? 65.0f : fi);
            float s  = xs - fi;
            float4 a = tab[tb + (int)fi];
            (&ov.x)[e] = fmaf(fmaf(fmaf(a.w, s, a.z), s, a.y), s, a.x);
        }
        op[idx] = ov;
    }

    // generic scalar tail (n % 4 != 0) — no-op for this problem's n
    for (int k = (n4 << 2) + gid; k < n; k += stride) {
        float xs = x[k] * 69.0f;
        float fi = floorf(xs);
        fi = fi < 3.0f ? 3.0f : (fi > 65.0f ? 65.0f : fi);
        float s  = xs - fi;
        float4 a = tab[tb + (int)fi];
        out[k] = fmaf(fmaf(fmaf(a.w, s, a.z), s, a.y), s, a.x);
    }
}

extern "C" void kernel_launch(void* const* d_in, const int* in_sizes, int n_in,
                              void* d_out, int out_size, void* d_ws, size_t ws_size,
                              hipStream_t stream) {
    const float* x    = (const float*)d_in[0];
    const float* coef = (const float*)d_in[1];
    float* out        = (float*)d_out;
    int n = in_sizes[0];

    // 8192 blocks x 256 thr = 2.097M threads; 16.77M float4 -> exactly 8
    // float4/thread, so every thread takes the 8-deep batched fast path.
    int threads = 256;
    int blocks  = 8192;
    int max_blocks = ((n >> 2) + threads - 1) / threads;
    if (max_blocks < 1) max_blocks = 1;
    if (blocks > max_blocks) blocks = max_blocks;

    spline_kernel<<<blocks, threads, 0, stream>>>(x, coef, out, n);
}